// Round 11
// baseline (676.622 us; speedup 1.0000x reference)
//
#include <hip/hip_runtime.h>

// RowAreaAttention split pipeline (round 11):
//  K0 prep_cvt: f32->f16 (w_qkv, w_proj, x)
//  K1 qkv_attn: per (128-row block, head): GEMM {Q|K|V} = xh @ wq_h^T (128x192x768)
//     BK=64, A staged in LDS (gload_lds, zero-conflict swizzle), B (weights)
//     streamed DIRECTLY from L2 into registers (no LDS) — halves LDS traffic.
//     8 waves as 2M x 4N (64x48 each). LDS 48 KB -> 3 WG/CU target.
//     Then in-WG 2x 64-token attention (round-9 overlay); writes only O.
//  K3 gemm_bt64: out = O @ wp16^T + bias (8-wave BK=64 structure, round-10)

#define SCALE 0.125f

typedef _Float16 h16;
typedef h16   half8 __attribute__((ext_vector_type(8)));
typedef float f32x4 __attribute__((ext_vector_type(4)));

typedef const __attribute__((address_space(1))) unsigned int ga_u32;
typedef __attribute__((address_space(3))) unsigned int ls_u32;

// swizzled h16 index into a [R][64] tile: 16B chunk (c>>3) XOR'd with (r&7)
#define SWZ(r, c) (((r) << 6) + ((((c) >> 3) ^ ((r) & 7)) << 3) + ((c) & 7))

// ---------------------------------------------------------------- K0: prep
__device__ __forceinline__ void cvt8(const float* __restrict__ s,
                                     h16* __restrict__ d, int i) {
  const float4 a = ((const float4*)s)[2 * i];
  const float4 b = ((const float4*)s)[2 * i + 1];
  half8 r;
  r[0] = (h16)a.x; r[1] = (h16)a.y; r[2] = (h16)a.z; r[3] = (h16)a.w;
  r[4] = (h16)b.x; r[5] = (h16)b.y; r[6] = (h16)b.z; r[7] = (h16)b.w;
  ((half8*)d)[i] = r;
}

__global__ void prep_cvt(const float* __restrict__ wq, const float* __restrict__ wp,
                         const float* __restrict__ x,
                         h16* __restrict__ wq16, h16* __restrict__ wp16,
                         h16* __restrict__ xh) {
  const int stride = gridDim.x * blockDim.x;
  const int t0 = blockIdx.x * blockDim.x + threadIdx.x;
  for (int i = t0; i < 221184; i += stride) cvt8(wq, wq16, i);   // 2304*768
  for (int i = t0; i < 73728;  i += stride) cvt8(wp, wp16, i);   // 768*768
  for (int i = t0; i < 6291456; i += stride) cvt8(x, xh, i);     // 65536*768
}

__global__ void prep_w_only(const float* __restrict__ wq, const float* __restrict__ wp,
                            h16* __restrict__ wq16, h16* __restrict__ wp16) {
  const int stride = gridDim.x * blockDim.x;
  const int t0 = blockIdx.x * blockDim.x + threadIdx.x;
  for (int i = t0; i < 221184; i += stride) cvt8(wq, wq16, i);
  for (int i = t0; i < 73728;  i += stride) cvt8(wp, wp16, i);
}

// -------------------------------------- K1: fused QKV-GEMM + attention per head
// Grid: 512 row-tiles x 12 heads, WG = 512 thr (8 waves, 2M x 4N: 64x48/wave).
// A (x) -> LDS dbuf via gload_lds (zero-conflict swizzle). B (weights) -> regs
// directly from global (L2-hot, 3.5 MB, 2 waves/frag redundancy ~ 17 TB/s).
__global__ __launch_bounds__(512, 6)
void qkv_attn(const h16* __restrict__ A,      // xh (65536 x 768)
              const h16* __restrict__ B,      // wq16 (2304 x 768)
              h16* __restrict__ O) {          // obuf (65536 x 768)
  __shared__ h16 smem[24576];                 // 48 KB union
  h16* As0 = smem;                            // GEMM: [2][8192] ([128][64] x2)
  h16* sQ  = smem;                            // attn: [128][64] swizzled
  h16* sK  = smem + 8192;                     // attn: [128][64] swizzled
  h16* sV  = smem + 16384;                    // attn: [2][64][64] swizzled (V^T)

  const int nwg = gridDim.x;                  // 6144
  const int bid = blockIdx.x;
  const int wg  = (bid & 7) * (nwg >> 3) + (bid >> 3);   // XCD-chunked swizzle
  const int mt = wg / 12, h = wg - mt * 12;
  const int m0 = mt * 128;

  const int tid  = threadIdx.x;
  const int lane = tid & 63;
  const int wv   = tid >> 6;       // 0..7
  const int l16  = lane & 15;
  const int kg   = lane >> 4;
  const int wr   = wv & 1;         // M half    (rows wr*64, 4 frags)
  const int wc   = wv >> 1;        // N quarter (cols wc*48, 3 frags)

  // ---- A staging: thread covers chunk (row = i*64 + tid>>3, slot = tid&7)
  const int srow = tid >> 3;                  // 0..63
  const int slot = tid & 7;
  const int cg   = slot ^ (srow & 7);         // pre-swizzled src col-group
  const h16* pA[2];
  int loA[2];
  #pragma unroll
  for (int i = 0; i < 2; ++i) {
    const int r = i * 64 + srow;                         // 0..127
    pA[i]  = A + (size_t)(m0 + r) * 768 + cg * 8;
    loA[i] = r * 64 + slot * 8;
  }

#define GLDS(srcp, ldsp)                                                       \
  __builtin_amdgcn_global_load_lds((ga_u32*)(const void*)(srcp),               \
                                   (ls_u32*)(void*)(ldsp), 16, 0, 0)
#define STAGE(bf, kt)                                                          \
  do {                                                                         \
    GLDS(pA[0] + (kt) * 64, &As0[(bf) * 8192 + loA[0]]);                       \
    GLDS(pA[1] + (kt) * 64, &As0[(bf) * 8192 + loA[1]]);                       \
  } while (0)

  // ---- B fragment pointers (direct global; K-contig rows of wq16)
  const h16* pBg[3];
  #pragma unroll
  for (int ni = 0; ni < 3; ++ni) {
    const int cbase = wc * 48 + ni * 16;                 // 0..176, wave-uniform
    const int gr = (cbase >> 6) * 768 + h * 64 + (cbase & 63) + l16;
    pBg[ni] = B + (size_t)gr * 768 + kg * 8;
  }

  // ---- A fragment read offsets (h16 units, swizzled; frag row&7 == l16&7)
  const int aBase = (wr * 64 + l16) * 64;     // + mi*1024 + axor[ks]
  int axor[2];
  #pragma unroll
  for (int ks = 0; ks < 2; ++ks)
    axor[ks] = ((ks * 4 + kg) ^ (l16 & 7)) * 8;

  f32x4 acc[4][3];
  #pragma unroll
  for (int mi = 0; mi < 4; ++mi)
    #pragma unroll
    for (int ni = 0; ni < 3; ++ni)
      acc[mi][ni] = (f32x4){0.f, 0.f, 0.f, 0.f};

  STAGE(0, 0);
  asm volatile("s_waitcnt vmcnt(0)" ::: "memory");
  __syncthreads();

  int cur = 0;
  for (int t = 0; t < 12; ++t) {
    if (t < 11) STAGE(cur ^ 1, t + 1);
    const h16* Ac = As0 + cur * 8192;
    #pragma unroll
    for (int ks = 0; ks < 2; ++ks) {
      half8 bf8[3];
      #pragma unroll
      for (int ni = 0; ni < 3; ++ni)
        bf8[ni] = *(const half8*)(pBg[ni] + t * 64 + ks * 32);
      half8 af[4];
      #pragma unroll
      for (int mi = 0; mi < 4; ++mi)
        af[mi] = *(const half8*)&Ac[aBase + mi * 1024 + axor[ks]];
      #pragma unroll
      for (int mi = 0; mi < 4; ++mi)
        #pragma unroll
        for (int ni = 0; ni < 3; ++ni)
          acc[mi][ni] = __builtin_amdgcn_mfma_f32_16x16x32_f16(af[mi], bf8[ni], acc[mi][ni], 0, 0, 0);
    }
    asm volatile("s_waitcnt vmcnt(0)" ::: "memory");
    __syncthreads();
    cur ^= 1;
  }
#undef STAGE
#undef GLDS

  // ---- scatter acc -> sQ / sK / sV (swizzled; all waves past final LDS reads)
  #pragma unroll
  for (int mi = 0; mi < 4; ++mi) {
    const int rowb = wr * 64 + mi * 16 + kg * 4;     // token row in 128
    const int r6   = rowb & 63;                      // token within group
    const int g2s  = rowb >> 6;                      // group of this row
    #pragma unroll
    for (int ni = 0; ni < 3; ++ni) {
      const int cbase = wc * 48 + ni * 16;           // wave-uniform, 0..176
      const int sel = cbase >> 6;
      const int d   = (cbase & 63) + l16;
      if (sel == 0) {
        #pragma unroll
        for (int j = 0; j < 4; ++j) sQ[SWZ(rowb + j, d)] = (h16)acc[mi][ni][j];
      } else if (sel == 1) {
        #pragma unroll
        for (int j = 0; j < 4; ++j) sK[SWZ(rowb + j, d)] = (h16)acc[mi][ni][j];
      } else {
        #pragma unroll
        for (int j = 0; j < 4; ++j) sV[g2s * 4096 + SWZ(d, r6 + j)] = (h16)acc[mi][ni][j];
      }
    }
  }
  __syncthreads();

  // ---- attention: wave handles 16 q-rows [wv*16, wv*16+16), group wv>>2
  const int qr0 = wv * 16;
  const int g2  = wv >> 2;
  const h16* sKg = sK + g2 * 4096;
  const h16* sVg = sV + g2 * 4096;

  f32x4 sacc[4];
  #pragma unroll
  for (int cb = 0; cb < 4; ++cb) sacc[cb] = (f32x4){0.f, 0.f, 0.f, 0.f};
  #pragma unroll
  for (int ks = 0; ks < 2; ++ks) {
    const half8 aq = *(const half8*)&sQ[(qr0 + l16) * 64 + axor[ks]];
    #pragma unroll
    for (int cb = 0; cb < 4; ++cb) {
      const half8 kf = *(const half8*)&sKg[(cb * 16 + l16) * 64 + axor[ks]];
      sacc[cb] = __builtin_amdgcn_mfma_f32_16x16x32_f16(aq, kf, sacc[cb], 0, 0, 0);
    }
  }

  // max-free softmax (|S*scale| << 88): rows qr0 + kg*4 + j
  float e[4][4], rs[4];
  #pragma unroll
  for (int j = 0; j < 4; ++j) {
    float t = 0.f;
    #pragma unroll
    for (int cb = 0; cb < 4; ++cb) { e[cb][j] = __expf(sacc[cb][j] * SCALE); t += e[cb][j]; }
    rs[j] = t;
  }
  #pragma unroll
  for (int m = 1; m < 16; m <<= 1)
    #pragma unroll
    for (int j = 0; j < 4; ++j) rs[j] += __shfl_xor(rs[j], m);
  #pragma unroll
  for (int j = 0; j < 4; ++j) rs[j] = __fdividef(1.0f, rs[j]);

  // P -> sQ (own rows only; no cross-wave readers of these rows)
  #pragma unroll
  for (int cb = 0; cb < 4; ++cb)
    #pragma unroll
    for (int j = 0; j < 4; ++j)
      sQ[SWZ(qr0 + kg * 4 + j, cb * 16 + l16)] = (h16)(e[cb][j] * rs[j]);
  __syncthreads();   // all K-reads done before O overwrites sK

  // ---- O = P V
  f32x4 oacc[4];
  #pragma unroll
  for (int cb = 0; cb < 4; ++cb) oacc[cb] = (f32x4){0.f, 0.f, 0.f, 0.f};
  #pragma unroll
  for (int ks = 0; ks < 2; ++ks) {
    const half8 ap = *(const half8*)&sQ[(qr0 + l16) * 64 + axor[ks]];
    #pragma unroll
    for (int cb = 0; cb < 4; ++cb) {
      const half8 vf = *(const half8*)&sVg[(cb * 16 + l16) * 64 + axor[ks]];
      oacc[cb] = __builtin_amdgcn_mfma_f32_16x16x32_f16(ap, vf, oacc[cb], 0, 0, 0);
    }
  }

  // O -> sK (dead), then chunk-permuted vectorized store (coalesced per segment)
  #pragma unroll
  for (int cb = 0; cb < 4; ++cb)
    #pragma unroll
    for (int j = 0; j < 4; ++j)
      sK[SWZ(qr0 + kg * 4 + j, cb * 16 + l16)] = (h16)oacc[cb][j];
  __syncthreads();
  #pragma unroll
  for (int c = tid; c < 1024; c += 512) {
    const int row = c >> 3, sl = c & 7;
    const int gch = sl ^ (row & 7);            // un-swizzle via permuted dst chunk
    *(half8*)(O + (size_t)(m0 + row) * 768 + h * 64 + gch * 8) =
        *(const half8*)&sK[row * 64 + sl * 8];
  }
}

// --------------------------- K3: gemm_bt64 (8-wave BK=64, round-10 structure)
__global__ __launch_bounds__(512, 4)
void gemm_bt64(const h16* __restrict__ A,
               const h16* __restrict__ B,
               const float* __restrict__ bias,
               float* __restrict__ C,
               int ntiles) {
  __shared__ h16 As0[2][8192];   // [128][64] swizzled x2
  __shared__ h16 Bs0[2][8192];

  const int nwg = gridDim.x;
  const int bid = blockIdx.x;
  const int wg  = (bid & 7) * (nwg >> 3) + (bid >> 3);
  const int mt = wg / ntiles, nt = wg - mt * ntiles;
  const int m0 = mt * 128, n0 = nt * 128;

  const int tid  = threadIdx.x;
  const int lane = tid & 63;
  const int wv   = tid >> 6;       // 0..7
  const int l16  = lane & 15;
  const int kg   = lane >> 4;
  const int wr   = wv & 3;         // M quarter (rows wr*32, 2 frags)
  const int wc   = wv >> 2;        // N half   (cols wc*64, 4 frags)

  const int srow = tid >> 3;
  const int slot = tid & 7;
  const int cg   = slot ^ (srow & 7);
  const h16* pA[2];
  const h16* pB[2];
  int lo[2];
  #pragma unroll
  for (int i = 0; i < 2; ++i) {
    const int r = i * 64 + srow;                 // 0..127
    pA[i] = A + (size_t)(m0 + r) * 768 + cg * 8;
    pB[i] = B + (size_t)(n0 + r) * 768 + cg * 8;
    lo[i] = r * 64 + slot * 8;
  }

#define GLDS(srcp, ldsp)                                                       \
  __builtin_amdgcn_global_load_lds((ga_u32*)(const void*)(srcp),               \
                                   (ls_u32*)(void*)(ldsp), 16, 0, 0)
#define STAGE(bf, kt)                                                          \
  do {                                                                         \
    GLDS(pA[0] + (kt) * 64, &As0[bf][lo[0]]);                                  \
    GLDS(pA[1] + (kt) * 64, &As0[bf][lo[1]]);                                  \
    GLDS(pB[0] + (kt) * 64, &Bs0[bf][lo[0]]);                                  \
    GLDS(pB[1] + (kt) * 64, &Bs0[bf][lo[1]]);                                  \
  } while (0)

  const int aBase = (wr * 32 + l16) * 64;
  const int bBase = (wc * 64 + l16) * 64;
  int axor[2];
  #pragma unroll
  for (int ks = 0; ks < 2; ++ks)
    axor[ks] = ((ks * 4 + kg) ^ (l16 & 7)) * 8;

  f32x4 acc[2][4];
  #pragma unroll
  for (int mi = 0; mi < 2; ++mi)
    #pragma unroll
    for (int ni = 0; ni < 4; ++ni)
      acc[mi][ni] = (f32x4){0.f, 0.f, 0.f, 0.f};

  STAGE(0, 0);
  asm volatile("s_waitcnt vmcnt(0)" ::: "memory");
  __syncthreads();

  int cur = 0;
  for (int t = 0; t < 12; ++t) {
    if (t < 11) STAGE(cur ^ 1, t + 1);
    #pragma unroll
    for (int ks = 0; ks < 2; ++ks) {
      half8 af[2], bf8[4];
      #pragma unroll
      for (int mi = 0; mi < 2; ++mi)
        af[mi] = *(const half8*)&As0[cur][aBase + mi * 1024 + axor[ks]];
      #pragma unroll
      for (int ni = 0; ni < 4; ++ni)
        bf8[ni] = *(const half8*)&Bs0[cur][bBase + ni * 1024 + axor[ks]];
      #pragma unroll
      for (int mi = 0; mi < 2; ++mi)
        #pragma unroll
        for (int ni = 0; ni < 4; ++ni)
          acc[mi][ni] = __builtin_amdgcn_mfma_f32_16x16x32_f16(af[mi], bf8[ni], acc[mi][ni], 0, 0, 0);
    }
    asm volatile("s_waitcnt vmcnt(0)" ::: "memory");
    __syncthreads();
    cur ^= 1;
  }
#undef STAGE
#undef GLDS

  float bv[4];
  #pragma unroll
  for (int ni = 0; ni < 4; ++ni) bv[ni] = bias[n0 + wc * 64 + ni * 16 + l16];
  #pragma unroll
  for (int mi = 0; mi < 2; ++mi) {
    #pragma unroll
    for (int ni = 0; ni < 4; ++ni) {
      const int col = n0 + wc * 64 + ni * 16 + l16;
      #pragma unroll
      for (int j = 0; j < 4; ++j) {
        const int row = m0 + wr * 32 + mi * 16 + kg * 4 + j;
        C[(size_t)row * 768 + col] = acc[mi][ni][j] + bv[ni];
      }
    }
  }
}

// ------------------------------------------- fallback: fused kernel (small ws)
template <typename WT>
__device__ __forceinline__ half8 loadw8(const WT* p);
template <>
__device__ __forceinline__ half8 loadw8<h16>(const h16* p) { return *(const half8*)p; }
template <>
__device__ __forceinline__ half8 loadw8<float>(const float* p) {
  const float4 a = *(const float4*)p;
  const float4 b = *(const float4*)(p + 4);
  half8 r;
  r[0] = (h16)a.x; r[1] = (h16)a.y; r[2] = (h16)a.z; r[3] = (h16)a.w;
  r[4] = (h16)b.x; r[5] = (h16)b.y; r[6] = (h16)b.z; r[7] = (h16)b.w;
  return r;
}

template <typename WT>
__launch_bounds__(512, 2)
__global__ void fused_fb(const float* __restrict__ x,
                         const WT* __restrict__ wq,
                         const WT* __restrict__ wp,
                         const float* __restrict__ bias,
                         float* __restrict__ out) {
  __shared__ h16   xs[64][776];
  __shared__ h16   qs[64][72];
  __shared__ h16   ks[64][72];
  __shared__ h16   vt[64][72];
  __shared__ float sS[64][68];

  const int g = blockIdx.x, tid = threadIdx.x;
  const int wv = tid >> 6, lane = tid & 63, l16 = lane & 15, kg = lane >> 4;

  const float* xg = x + (size_t)g * (64 * 768);
  #pragma unroll
  for (int i = 0; i < 24; ++i) {
    const int idx = tid + i * 512;
    const int row = idx / 192;
    const int c4  = (idx - row * 192) * 4;
    const float4 v = ((const float4*)xg)[idx];
    h16* p = &xs[row][c4];
    p[0] = (h16)v.x; p[1] = (h16)v.y; p[2] = (h16)v.z; p[3] = (h16)v.w;
  }

  f32x4 acc[4][6];
  #pragma unroll
  for (int a = 0; a < 4; ++a)
    #pragma unroll
    for (int b = 0; b < 6; ++b) acc[a][b] = (f32x4){0.f, 0.f, 0.f, 0.f};

  float bcol[6];
  #pragma unroll
  for (int cb = 0; cb < 6; ++cb) bcol[cb] = bias[wv * 96 + cb * 16 + l16];

  const int r0 = (wv & 1) * 32, c0 = (wv >> 1) * 48;
  const int rS = (wv >> 1) * 16, cS = (wv & 1) * 32;
  __syncthreads();

  for (int h = 0; h < 12; ++h) {
    f32x4 facc[2][3];
    #pragma unroll
    for (int a = 0; a < 2; ++a)
      #pragma unroll
      for (int b = 0; b < 3; ++b) facc[a][b] = (f32x4){0.f, 0.f, 0.f, 0.f};
    int wrow[3];
    #pragma unroll
    for (int cb = 0; cb < 3; ++cb) {
      const int n = c0 + cb * 16;
      wrow[cb] = (n >> 6) * 768 + h * 64 + (n & 63) + l16;
    }
    for (int k0 = 0; k0 < 768; k0 += 32) {
      const half8 a0 = *(const half8*)&xs[r0 + l16][k0 + kg * 8];
      const half8 a1 = *(const half8*)&xs[r0 + 16 + l16][k0 + kg * 8];
      #pragma unroll
      for (int cb = 0; cb < 3; ++cb) {
        const half8 b = loadw8<WT>(wq + (size_t)wrow[cb] * 768 + k0 + kg * 8);
        facc[0][cb] = __builtin_amdgcn_mfma_f32_16x16x32_f16(a0, b, facc[0][cb], 0, 0, 0);
        facc[1][cb] = __builtin_amdgcn_mfma_f32_16x16x32_f16(a1, b, facc[1][cb], 0, 0, 0);
      }
    }
    #pragma unroll
    for (int rb = 0; rb < 2; ++rb)
      #pragma unroll
      for (int cb = 0; cb < 3; ++cb) {
        const int col = c0 + cb * 16 + l16;
        const int rowb = r0 + rb * 16 + kg * 4;
        if (col < 64) {
          #pragma unroll
          for (int j = 0; j < 4; ++j) qs[rowb + j][col] = (h16)facc[rb][cb][j];
        } else if (col < 128) {
          #pragma unroll
          for (int j = 0; j < 4; ++j) ks[rowb + j][col - 64] = (h16)facc[rb][cb][j];
        } else {
          #pragma unroll
          for (int j = 0; j < 4; ++j) vt[col - 128][rowb + j] = (h16)facc[rb][cb][j];
        }
      }
    __syncthreads();

    f32x4 sacc[2];
    sacc[0] = (f32x4){0.f, 0.f, 0.f, 0.f};
    sacc[1] = (f32x4){0.f, 0.f, 0.f, 0.f};
    #pragma unroll
    for (int k0 = 0; k0 < 64; k0 += 32) {
      const half8 aq = *(const half8*)&qs[rS + l16][k0 + kg * 8];
      const half8 b0 = *(const half8*)&ks[cS + l16][k0 + kg * 8];
      const half8 b1 = *(const half8*)&ks[cS + 16 + l16][k0 + kg * 8];
      sacc[0] = __builtin_amdgcn_mfma_f32_16x16x32_f16(aq, b0, sacc[0], 0, 0, 0);
      sacc[1] = __builtin_amdgcn_mfma_f32_16x16x32_f16(aq, b1, sacc[1], 0, 0, 0);
    }
    #pragma unroll
    for (int t = 0; t < 2; ++t)
      #pragma unroll
      for (int j = 0; j < 4; ++j)
        sS[rS + kg * 4 + j][cS + t * 16 + l16] = sacc[t][j] * SCALE;
    __syncthreads();

    {
      const int row = tid >> 3, j0 = (tid & 7) * 8;
      float v0[8];
      #pragma unroll
      for (int i = 0; i < 8; ++i) v0[i] = sS[row][j0 + i];
      float m = v0[0];
      #pragma unroll
      for (int i = 1; i < 8; ++i) m = fmaxf(m, v0[i]);
      m = fmaxf(m, __shfl_xor(m, 1));
      m = fmaxf(m, __shfl_xor(m, 2));
      m = fmaxf(m, __shfl_xor(m, 4));
      float e[8], ssum = 0.f;
      #pragma unroll
      for (int i = 0; i < 8; ++i) { e[i] = __expf(v0[i] - m); ssum += e[i]; }
      ssum += __shfl_xor(ssum, 1);
      ssum += __shfl_xor(ssum, 2);
      ssum += __shfl_xor(ssum, 4);
      const float inv = 1.0f / ssum;
      #pragma unroll
      for (int i = 0; i < 8; ++i) qs[row][j0 + i] = (h16)(e[i] * inv);
    }
    __syncthreads();

    f32x4 oacc[2];
    oacc[0] = (f32x4){0.f, 0.f, 0.f, 0.f};
    oacc[1] = (f32x4){0.f, 0.f, 0.f, 0.f};
    #pragma unroll
    for (int k0 = 0; k0 < 64; k0 += 32) {
      const half8 ap = *(const half8*)&qs[rS + l16][k0 + kg * 8];
      const half8 b0 = *(const half8*)&vt[cS + l16][k0 + kg * 8];
      const half8 b1 = *(const half8*)&vt[cS + 16 + l16][k0 + kg * 8];
      oacc[0] = __builtin_amdgcn_mfma_f32_16x16x32_f16(ap, b0, oacc[0], 0, 0, 0);
      oacc[1] = __builtin_amdgcn_mfma_f32_16x16x32_f16(ap, b1, oacc[1], 0, 0, 0);
    }
    #pragma unroll
    for (int t = 0; t < 2; ++t)
      #pragma unroll
      for (int j = 0; j < 4; ++j)
        ks[rS + kg * 4 + j][cS + t * 16 + l16] = (h16)oacc[t][j];
    __syncthreads();

    #pragma unroll
    for (int k0 = 0; k0 < 64; k0 += 32) {
      half8 ah[4];
      #pragma unroll
      for (int rb = 0; rb < 4; ++rb)
        ah[rb] = *(const half8*)&ks[rb * 16 + l16][k0 + kg * 8];
      #pragma unroll
      for (int cb = 0; cb < 6; ++cb) {
        const int ocol = wv * 96 + cb * 16 + l16;
        const half8 bw = loadw8<WT>(wp + (size_t)ocol * 768 + h * 64 + k0 + kg * 8);
        #pragma unroll
        for (int rb = 0; rb < 4; ++rb)
          acc[rb][cb] = __builtin_amdgcn_mfma_f32_16x16x32_f16(ah[rb], bw, acc[rb][cb], 0, 0, 0);
      }
    }
    __syncthreads();
  }

  float* og = out + (size_t)g * (64 * 768);
  #pragma unroll
  for (int rb = 0; rb < 4; ++rb)
    #pragma unroll
    for (int cb = 0; cb < 6; ++cb) {
      const int col = wv * 96 + cb * 16 + l16;
      #pragma unroll
      for (int j = 0; j < 4; ++j) {
        const int row = rb * 16 + kg * 4 + j;
        og[(size_t)row * 768 + col] = acc[rb][cb][j] + bcol[cb];
      }
    }
}

// ---------------------------------------------------------------- launch
extern "C" void kernel_launch(void* const* d_in, const int* in_sizes, int n_in,
                              void* d_out, int out_size, void* d_ws, size_t ws_size,
                              hipStream_t stream) {
  const float* x     = (const float*)d_in[0];
  const float* wqkv  = (const float*)d_in[1];
  const float* wproj = (const float*)d_in[2];
  const float* bias  = (const float*)d_in[3];
  float* out = (float*)d_out;

  const size_t SZ_WQ = (size_t)2304 * 768 * sizeof(h16);   //   3.54 MB
  const size_t SZ_WP = (size_t)768 * 768 * sizeof(h16);    //   1.18 MB
  const size_t SZ_XH = (size_t)65536 * 768 * sizeof(h16);  // 100.66 MB
  const size_t SZ_O  = (size_t)65536 * 768 * sizeof(h16);  // 100.66 MB

  if (ws_size >= SZ_WQ + SZ_WP + SZ_XH + SZ_O) {
    h16* wq16 = (h16*)d_ws;
    h16* wp16 = (h16*)((char*)d_ws + SZ_WQ);
    h16* xh   = (h16*)((char*)d_ws + SZ_WQ + SZ_WP);
    h16* obuf = (h16*)((char*)d_ws + SZ_WQ + SZ_WP + SZ_XH);

    prep_cvt<<<2048, 256, 0, stream>>>(wqkv, wproj, x, wq16, wp16, xh);
    qkv_attn<<<6144, 512, 0, stream>>>(xh, wq16, obuf);
    gemm_bt64<<<3072, 512, 0, stream>>>(obuf, wp16, bias, out, 6);
  } else if (ws_size >= SZ_WQ + SZ_WP) {
    h16* wq16 = (h16*)d_ws;
    h16* wp16 = (h16*)((char*)d_ws + SZ_WQ);
    prep_w_only<<<512, 256, 0, stream>>>(wqkv, wproj, wq16, wp16);
    fused_fb<h16><<<1024, 512, 0, stream>>>(x, wq16, wp16, bias, out);
  } else {
    fused_fb<float><<<1024, 512, 0, stream>>>(x, wqkv, wproj, bias, out);
  }
}

// Round 12
// 642.432 us; speedup vs baseline: 1.0532x; 1.0532x over previous
//
#include <hip/hip_runtime.h>

// RowAreaAttention split pipeline (round 12):
//  K0 prep_cvt: f32->f16 (w_qkv, w_proj, x)
//  K1 qkv_attn: per (128-row block, head): GEMM {Q|K|V} = xh @ wq_h^T (128x192x768)
//     BK=64, A staged in LDS (gload_lds, zero-conflict swizzle), B (weights)
//     streamed DIRECTLY from L2 into registers. 8 waves 2Mx4N. LDS 48 KB.
//     launch_bounds(512,4) — round-11's (512,6) forced a VGPR spill (VGPR=40,
//     WRITE 4x): allocator must keep acc in regs; LDS still allows 3 WG/CU.
//     Then in-WG 2x 64-token attention (round-9 overlay); writes only O.
//  K3 gemm_bt64: out = O @ wp16^T + bias (8-wave BK=64 structure, round-10)

#define SCALE 0.125f

typedef _Float16 h16;
typedef h16   half8 __attribute__((ext_vector_type(8)));
typedef float f32x4 __attribute__((ext_vector_type(4)));

typedef const __attribute__((address_space(1))) unsigned int ga_u32;
typedef __attribute__((address_space(3))) unsigned int ls_u32;

// swizzled h16 index into a [R][64] tile: 16B chunk (c>>3) XOR'd with (r&7)
#define SWZ(r, c) (((r) << 6) + ((((c) >> 3) ^ ((r) & 7)) << 3) + ((c) & 7))

// ---------------------------------------------------------------- K0: prep
__device__ __forceinline__ void cvt8(const float* __restrict__ s,
                                     h16* __restrict__ d, int i) {
  const float4 a = ((const float4*)s)[2 * i];
  const float4 b = ((const float4*)s)[2 * i + 1];
  half8 r;
  r[0] = (h16)a.x; r[1] = (h16)a.y; r[2] = (h16)a.z; r[3] = (h16)a.w;
  r[4] = (h16)b.x; r[5] = (h16)b.y; r[6] = (h16)b.z; r[7] = (h16)b.w;
  ((half8*)d)[i] = r;
}

__global__ void prep_cvt(const float* __restrict__ wq, const float* __restrict__ wp,
                         const float* __restrict__ x,
                         h16* __restrict__ wq16, h16* __restrict__ wp16,
                         h16* __restrict__ xh) {
  const int stride = gridDim.x * blockDim.x;
  const int t0 = blockIdx.x * blockDim.x + threadIdx.x;
  for (int i = t0; i < 221184; i += stride) cvt8(wq, wq16, i);   // 2304*768
  for (int i = t0; i < 73728;  i += stride) cvt8(wp, wp16, i);   // 768*768
  for (int i = t0; i < 6291456; i += stride) cvt8(x, xh, i);     // 65536*768
}

__global__ void prep_w_only(const float* __restrict__ wq, const float* __restrict__ wp,
                            h16* __restrict__ wq16, h16* __restrict__ wp16) {
  const int stride = gridDim.x * blockDim.x;
  const int t0 = blockIdx.x * blockDim.x + threadIdx.x;
  for (int i = t0; i < 221184; i += stride) cvt8(wq, wq16, i);
  for (int i = t0; i < 73728;  i += stride) cvt8(wp, wp16, i);
}

// -------------------------------------- K1: fused QKV-GEMM + attention per head
// Grid: 512 row-tiles x 12 heads, WG = 512 thr (8 waves, 2M x 4N: 64x48/wave).
// A (x) -> LDS dbuf via gload_lds (zero-conflict swizzle). B (weights) -> regs
// directly from global (L2-hot, 3.5 MB, 2 waves/frag redundancy ~ 17 TB/s).
__global__ __launch_bounds__(512, 4)
void qkv_attn(const h16* __restrict__ A,      // xh (65536 x 768)
              const h16* __restrict__ B,      // wq16 (2304 x 768)
              h16* __restrict__ O) {          // obuf (65536 x 768)
  __shared__ h16 smem[24576];                 // 48 KB union
  h16* As0 = smem;                            // GEMM: [2][8192] ([128][64] x2)
  h16* sQ  = smem;                            // attn: [128][64] swizzled
  h16* sK  = smem + 8192;                     // attn: [128][64] swizzled
  h16* sV  = smem + 16384;                    // attn: [2][64][64] swizzled (V^T)

  const int nwg = gridDim.x;                  // 6144
  const int bid = blockIdx.x;
  const int wg  = (bid & 7) * (nwg >> 3) + (bid >> 3);   // XCD-chunked swizzle
  const int mt = wg / 12, h = wg - mt * 12;
  const int m0 = mt * 128;

  const int tid  = threadIdx.x;
  const int lane = tid & 63;
  const int wv   = tid >> 6;       // 0..7
  const int l16  = lane & 15;
  const int kg   = lane >> 4;
  const int wr   = wv & 1;         // M half    (rows wr*64, 4 frags)
  const int wc   = wv >> 1;        // N quarter (cols wc*48, 3 frags)

  // ---- A staging: thread covers chunk (row = i*64 + tid>>3, slot = tid&7)
  const int srow = tid >> 3;                  // 0..63
  const int slot = tid & 7;
  const int cg   = slot ^ (srow & 7);         // pre-swizzled src col-group
  const h16* pA[2];
  int loA[2];
  #pragma unroll
  for (int i = 0; i < 2; ++i) {
    const int r = i * 64 + srow;                         // 0..127
    pA[i]  = A + (size_t)(m0 + r) * 768 + cg * 8;
    loA[i] = r * 64 + slot * 8;
  }

#define GLDS(srcp, ldsp)                                                       \
  __builtin_amdgcn_global_load_lds((ga_u32*)(const void*)(srcp),               \
                                   (ls_u32*)(void*)(ldsp), 16, 0, 0)
#define STAGE(bf, kt)                                                          \
  do {                                                                         \
    GLDS(pA[0] + (kt) * 64, &As0[(bf) * 8192 + loA[0]]);                       \
    GLDS(pA[1] + (kt) * 64, &As0[(bf) * 8192 + loA[1]]);                       \
  } while (0)

  // ---- B fragment pointers (direct global; K-contig rows of wq16)
  const h16* pBg[3];
  #pragma unroll
  for (int ni = 0; ni < 3; ++ni) {
    const int cbase = wc * 48 + ni * 16;                 // 0..176, wave-uniform
    const int gr = (cbase >> 6) * 768 + h * 64 + (cbase & 63) + l16;
    pBg[ni] = B + (size_t)gr * 768 + kg * 8;
  }

  // ---- A fragment read offsets (h16 units, swizzled; frag row&7 == l16&7)
  const int aBase = (wr * 64 + l16) * 64;     // + mi*1024 + axor[ks]
  int axor[2];
  #pragma unroll
  for (int ks = 0; ks < 2; ++ks)
    axor[ks] = ((ks * 4 + kg) ^ (l16 & 7)) * 8;

  f32x4 acc[4][3];
  #pragma unroll
  for (int mi = 0; mi < 4; ++mi)
    #pragma unroll
    for (int ni = 0; ni < 3; ++ni)
      acc[mi][ni] = (f32x4){0.f, 0.f, 0.f, 0.f};

  STAGE(0, 0);
  asm volatile("s_waitcnt vmcnt(0)" ::: "memory");
  __syncthreads();

  int cur = 0;
  for (int t = 0; t < 12; ++t) {
    if (t < 11) STAGE(cur ^ 1, t + 1);
    const h16* Ac = As0 + cur * 8192;
    #pragma unroll
    for (int ks = 0; ks < 2; ++ks) {
      half8 bf8[3];
      #pragma unroll
      for (int ni = 0; ni < 3; ++ni)
        bf8[ni] = *(const half8*)(pBg[ni] + t * 64 + ks * 32);
      half8 af[4];
      #pragma unroll
      for (int mi = 0; mi < 4; ++mi)
        af[mi] = *(const half8*)&Ac[aBase + mi * 1024 + axor[ks]];
      #pragma unroll
      for (int mi = 0; mi < 4; ++mi)
        #pragma unroll
        for (int ni = 0; ni < 3; ++ni)
          acc[mi][ni] = __builtin_amdgcn_mfma_f32_16x16x32_f16(af[mi], bf8[ni], acc[mi][ni], 0, 0, 0);
    }
    asm volatile("s_waitcnt vmcnt(0)" ::: "memory");
    __syncthreads();
    cur ^= 1;
  }
#undef STAGE
#undef GLDS

  // ---- scatter acc -> sQ / sK / sV (swizzled; all waves past final LDS reads)
  #pragma unroll
  for (int mi = 0; mi < 4; ++mi) {
    const int rowb = wr * 64 + mi * 16 + kg * 4;     // token row in 128
    const int r6   = rowb & 63;                      // token within group
    const int g2s  = rowb >> 6;                      // group of this row
    #pragma unroll
    for (int ni = 0; ni < 3; ++ni) {
      const int cbase = wc * 48 + ni * 16;           // wave-uniform, 0..176
      const int sel = cbase >> 6;
      const int d   = (cbase & 63) + l16;
      if (sel == 0) {
        #pragma unroll
        for (int j = 0; j < 4; ++j) sQ[SWZ(rowb + j, d)] = (h16)acc[mi][ni][j];
      } else if (sel == 1) {
        #pragma unroll
        for (int j = 0; j < 4; ++j) sK[SWZ(rowb + j, d)] = (h16)acc[mi][ni][j];
      } else {
        #pragma unroll
        for (int j = 0; j < 4; ++j) sV[g2s * 4096 + SWZ(d, r6 + j)] = (h16)acc[mi][ni][j];
      }
    }
  }
  __syncthreads();

  // ---- attention: wave handles 16 q-rows [wv*16, wv*16+16), group wv>>2
  const int qr0 = wv * 16;
  const int g2  = wv >> 2;
  const h16* sKg = sK + g2 * 4096;
  const h16* sVg = sV + g2 * 4096;

  f32x4 sacc[4];
  #pragma unroll
  for (int cb = 0; cb < 4; ++cb) sacc[cb] = (f32x4){0.f, 0.f, 0.f, 0.f};
  #pragma unroll
  for (int ks = 0; ks < 2; ++ks) {
    const half8 aq = *(const half8*)&sQ[(qr0 + l16) * 64 + axor[ks]];
    #pragma unroll
    for (int cb = 0; cb < 4; ++cb) {
      const half8 kf = *(const half8*)&sKg[(cb * 16 + l16) * 64 + axor[ks]];
      sacc[cb] = __builtin_amdgcn_mfma_f32_16x16x32_f16(aq, kf, sacc[cb], 0, 0, 0);
    }
  }

  // max-free softmax (|S*scale| << 88): rows qr0 + kg*4 + j
  float e[4][4], rs[4];
  #pragma unroll
  for (int j = 0; j < 4; ++j) {
    float t = 0.f;
    #pragma unroll
    for (int cb = 0; cb < 4; ++cb) { e[cb][j] = __expf(sacc[cb][j] * SCALE); t += e[cb][j]; }
    rs[j] = t;
  }
  #pragma unroll
  for (int m = 1; m < 16; m <<= 1)
    #pragma unroll
    for (int j = 0; j < 4; ++j) rs[j] += __shfl_xor(rs[j], m);
  #pragma unroll
  for (int j = 0; j < 4; ++j) rs[j] = __fdividef(1.0f, rs[j]);

  // P -> sQ (own rows only; no cross-wave readers of these rows)
  #pragma unroll
  for (int cb = 0; cb < 4; ++cb)
    #pragma unroll
    for (int j = 0; j < 4; ++j)
      sQ[SWZ(qr0 + kg * 4 + j, cb * 16 + l16)] = (h16)(e[cb][j] * rs[j]);
  __syncthreads();   // all K-reads done before O overwrites sK

  // ---- O = P V
  f32x4 oacc[4];
  #pragma unroll
  for (int cb = 0; cb < 4; ++cb) oacc[cb] = (f32x4){0.f, 0.f, 0.f, 0.f};
  #pragma unroll
  for (int ks = 0; ks < 2; ++ks) {
    const half8 ap = *(const half8*)&sQ[(qr0 + l16) * 64 + axor[ks]];
    #pragma unroll
    for (int cb = 0; cb < 4; ++cb) {
      const half8 vf = *(const half8*)&sVg[(cb * 16 + l16) * 64 + axor[ks]];
      oacc[cb] = __builtin_amdgcn_mfma_f32_16x16x32_f16(ap, vf, oacc[cb], 0, 0, 0);
    }
  }

  // O -> sK (dead), then chunk-permuted vectorized store (coalesced per segment)
  #pragma unroll
  for (int cb = 0; cb < 4; ++cb)
    #pragma unroll
    for (int j = 0; j < 4; ++j)
      sK[SWZ(qr0 + kg * 4 + j, cb * 16 + l16)] = (h16)oacc[cb][j];
  __syncthreads();
  #pragma unroll
  for (int c = tid; c < 1024; c += 512) {
    const int row = c >> 3, sl = c & 7;
    const int gch = sl ^ (row & 7);            // un-swizzle via permuted dst chunk
    *(half8*)(O + (size_t)(m0 + row) * 768 + h * 64 + gch * 8) =
        *(const half8*)&sK[row * 64 + sl * 8];
  }
}

// --------------------------- K3: gemm_bt64 (8-wave BK=64, round-10 structure)
__global__ __launch_bounds__(512, 4)
void gemm_bt64(const h16* __restrict__ A,
               const h16* __restrict__ B,
               const float* __restrict__ bias,
               float* __restrict__ C,
               int ntiles) {
  __shared__ h16 As0[2][8192];   // [128][64] swizzled x2
  __shared__ h16 Bs0[2][8192];

  const int nwg = gridDim.x;
  const int bid = blockIdx.x;
  const int wg  = (bid & 7) * (nwg >> 3) + (bid >> 3);
  const int mt = wg / ntiles, nt = wg - mt * ntiles;
  const int m0 = mt * 128, n0 = nt * 128;

  const int tid  = threadIdx.x;
  const int lane = tid & 63;
  const int wv   = tid >> 6;       // 0..7
  const int l16  = lane & 15;
  const int kg   = lane >> 4;
  const int wr   = wv & 3;         // M quarter (rows wr*32, 2 frags)
  const int wc   = wv >> 2;        // N half   (cols wc*64, 4 frags)

  const int srow = tid >> 3;
  const int slot = tid & 7;
  const int cg   = slot ^ (srow & 7);
  const h16* pA[2];
  const h16* pB[2];
  int lo[2];
  #pragma unroll
  for (int i = 0; i < 2; ++i) {
    const int r = i * 64 + srow;                 // 0..127
    pA[i] = A + (size_t)(m0 + r) * 768 + cg * 8;
    pB[i] = B + (size_t)(n0 + r) * 768 + cg * 8;
    lo[i] = r * 64 + slot * 8;
  }

#define GLDS(srcp, ldsp)                                                       \
  __builtin_amdgcn_global_load_lds((ga_u32*)(const void*)(srcp),               \
                                   (ls_u32*)(void*)(ldsp), 16, 0, 0)
#define STAGE(bf, kt)                                                          \
  do {                                                                         \
    GLDS(pA[0] + (kt) * 64, &As0[bf][lo[0]]);                                  \
    GLDS(pA[1] + (kt) * 64, &As0[bf][lo[1]]);                                  \
    GLDS(pB[0] + (kt) * 64, &Bs0[bf][lo[0]]);                                  \
    GLDS(pB[1] + (kt) * 64, &Bs0[bf][lo[1]]);                                  \
  } while (0)

  const int aBase = (wr * 32 + l16) * 64;
  const int bBase = (wc * 64 + l16) * 64;
  int axor[2];
  #pragma unroll
  for (int ks = 0; ks < 2; ++ks)
    axor[ks] = ((ks * 4 + kg) ^ (l16 & 7)) * 8;

  f32x4 acc[2][4];
  #pragma unroll
  for (int mi = 0; mi < 2; ++mi)
    #pragma unroll
    for (int ni = 0; ni < 4; ++ni)
      acc[mi][ni] = (f32x4){0.f, 0.f, 0.f, 0.f};

  STAGE(0, 0);
  asm volatile("s_waitcnt vmcnt(0)" ::: "memory");
  __syncthreads();

  int cur = 0;
  for (int t = 0; t < 12; ++t) {
    if (t < 11) STAGE(cur ^ 1, t + 1);
    #pragma unroll
    for (int ks = 0; ks < 2; ++ks) {
      half8 af[2], bf8[4];
      #pragma unroll
      for (int mi = 0; mi < 2; ++mi)
        af[mi] = *(const half8*)&As0[cur][aBase + mi * 1024 + axor[ks]];
      #pragma unroll
      for (int ni = 0; ni < 4; ++ni)
        bf8[ni] = *(const half8*)&Bs0[cur][bBase + ni * 1024 + axor[ks]];
      #pragma unroll
      for (int mi = 0; mi < 2; ++mi)
        #pragma unroll
        for (int ni = 0; ni < 4; ++ni)
          acc[mi][ni] = __builtin_amdgcn_mfma_f32_16x16x32_f16(af[mi], bf8[ni], acc[mi][ni], 0, 0, 0);
    }
    asm volatile("s_waitcnt vmcnt(0)" ::: "memory");
    __syncthreads();
    cur ^= 1;
  }
#undef STAGE
#undef GLDS

  float bv[4];
  #pragma unroll
  for (int ni = 0; ni < 4; ++ni) bv[ni] = bias[n0 + wc * 64 + ni * 16 + l16];
  #pragma unroll
  for (int mi = 0; mi < 2; ++mi) {
    #pragma unroll
    for (int ni = 0; ni < 4; ++ni) {
      const int col = n0 + wc * 64 + ni * 16 + l16;
      #pragma unroll
      for (int j = 0; j < 4; ++j) {
        const int row = m0 + wr * 32 + mi * 16 + kg * 4 + j;
        C[(size_t)row * 768 + col] = acc[mi][ni][j] + bv[ni];
      }
    }
  }
}

// ------------------------------------------- fallback: fused kernel (small ws)
template <typename WT>
__device__ __forceinline__ half8 loadw8(const WT* p);
template <>
__device__ __forceinline__ half8 loadw8<h16>(const h16* p) { return *(const half8*)p; }
template <>
__device__ __forceinline__ half8 loadw8<float>(const float* p) {
  const float4 a = *(const float4*)p;
  const float4 b = *(const float4*)(p + 4);
  half8 r;
  r[0] = (h16)a.x; r[1] = (h16)a.y; r[2] = (h16)a.z; r[3] = (h16)a.w;
  r[4] = (h16)b.x; r[5] = (h16)b.y; r[6] = (h16)b.z; r[7] = (h16)b.w;
  return r;
}

template <typename WT>
__launch_bounds__(512, 2)
__global__ void fused_fb(const float* __restrict__ x,
                         const WT* __restrict__ wq,
                         const WT* __restrict__ wp,
                         const float* __restrict__ bias,
                         float* __restrict__ out) {
  __shared__ h16   xs[64][776];
  __shared__ h16   qs[64][72];
  __shared__ h16   ks[64][72];
  __shared__ h16   vt[64][72];
  __shared__ float sS[64][68];

  const int g = blockIdx.x, tid = threadIdx.x;
  const int wv = tid >> 6, lane = tid & 63, l16 = lane & 15, kg = lane >> 4;

  const float* xg = x + (size_t)g * (64 * 768);
  #pragma unroll
  for (int i = 0; i < 24; ++i) {
    const int idx = tid + i * 512;
    const int row = idx / 192;
    const int c4  = (idx - row * 192) * 4;
    const float4 v = ((const float4*)xg)[idx];
    h16* p = &xs[row][c4];
    p[0] = (h16)v.x; p[1] = (h16)v.y; p[2] = (h16)v.z; p[3] = (h16)v.w;
  }

  f32x4 acc[4][6];
  #pragma unroll
  for (int a = 0; a < 4; ++a)
    #pragma unroll
    for (int b = 0; b < 6; ++b) acc[a][b] = (f32x4){0.f, 0.f, 0.f, 0.f};

  float bcol[6];
  #pragma unroll
  for (int cb = 0; cb < 6; ++cb) bcol[cb] = bias[wv * 96 + cb * 16 + l16];

  const int r0 = (wv & 1) * 32, c0 = (wv >> 1) * 48;
  const int rS = (wv >> 1) * 16, cS = (wv & 1) * 32;
  __syncthreads();

  for (int h = 0; h < 12; ++h) {
    f32x4 facc[2][3];
    #pragma unroll
    for (int a = 0; a < 2; ++a)
      #pragma unroll
      for (int b = 0; b < 3; ++b) facc[a][b] = (f32x4){0.f, 0.f, 0.f, 0.f};
    int wrow[3];
    #pragma unroll
    for (int cb = 0; cb < 3; ++cb) {
      const int n = c0 + cb * 16;
      wrow[cb] = (n >> 6) * 768 + h * 64 + (n & 63) + l16;
    }
    for (int k0 = 0; k0 < 768; k0 += 32) {
      const half8 a0 = *(const half8*)&xs[r0 + l16][k0 + kg * 8];
      const half8 a1 = *(const half8*)&xs[r0 + 16 + l16][k0 + kg * 8];
      #pragma unroll
      for (int cb = 0; cb < 3; ++cb) {
        const half8 b = loadw8<WT>(wq + (size_t)wrow[cb] * 768 + k0 + kg * 8);
        facc[0][cb] = __builtin_amdgcn_mfma_f32_16x16x32_f16(a0, b, facc[0][cb], 0, 0, 0);
        facc[1][cb] = __builtin_amdgcn_mfma_f32_16x16x32_f16(a1, b, facc[1][cb], 0, 0, 0);
      }
    }
    #pragma unroll
    for (int rb = 0; rb < 2; ++rb)
      #pragma unroll
      for (int cb = 0; cb < 3; ++cb) {
        const int col = c0 + cb * 16 + l16;
        const int rowb = r0 + rb * 16 + kg * 4;
        if (col < 64) {
          #pragma unroll
          for (int j = 0; j < 4; ++j) qs[rowb + j][col] = (h16)facc[rb][cb][j];
        } else if (col < 128) {
          #pragma unroll
          for (int j = 0; j < 4; ++j) ks[rowb + j][col - 64] = (h16)facc[rb][cb][j];
        } else {
          #pragma unroll
          for (int j = 0; j < 4; ++j) vt[col - 128][rowb + j] = (h16)facc[rb][cb][j];
        }
      }
    __syncthreads();

    f32x4 sacc[2];
    sacc[0] = (f32x4){0.f, 0.f, 0.f, 0.f};
    sacc[1] = (f32x4){0.f, 0.f, 0.f, 0.f};
    #pragma unroll
    for (int k0 = 0; k0 < 64; k0 += 32) {
      const half8 aq = *(const half8*)&qs[rS + l16][k0 + kg * 8];
      const half8 b0 = *(const half8*)&ks[cS + l16][k0 + kg * 8];
      const half8 b1 = *(const half8*)&ks[cS + 16 + l16][k0 + kg * 8];
      sacc[0] = __builtin_amdgcn_mfma_f32_16x16x32_f16(aq, b0, sacc[0], 0, 0, 0);
      sacc[1] = __builtin_amdgcn_mfma_f32_16x16x32_f16(aq, b1, sacc[1], 0, 0, 0);
    }
    #pragma unroll
    for (int t = 0; t < 2; ++t)
      #pragma unroll
      for (int j = 0; j < 4; ++j)
        sS[rS + kg * 4 + j][cS + t * 16 + l16] = sacc[t][j] * SCALE;
    __syncthreads();

    {
      const int row = tid >> 3, j0 = (tid & 7) * 8;
      float v0[8];
      #pragma unroll
      for (int i = 0; i < 8; ++i) v0[i] = sS[row][j0 + i];
      float m = v0[0];
      #pragma unroll
      for (int i = 1; i < 8; ++i) m = fmaxf(m, v0[i]);
      m = fmaxf(m, __shfl_xor(m, 1));
      m = fmaxf(m, __shfl_xor(m, 2));
      m = fmaxf(m, __shfl_xor(m, 4));
      float e[8], ssum = 0.f;
      #pragma unroll
      for (int i = 0; i < 8; ++i) { e[i] = __expf(v0[i] - m); ssum += e[i]; }
      ssum += __shfl_xor(ssum, 1);
      ssum += __shfl_xor(ssum, 2);
      ssum += __shfl_xor(ssum, 4);
      const float inv = 1.0f / ssum;
      #pragma unroll
      for (int i = 0; i < 8; ++i) qs[row][j0 + i] = (h16)(e[i] * inv);
    }
    __syncthreads();

    f32x4 oacc[2];
    oacc[0] = (f32x4){0.f, 0.f, 0.f, 0.f};
    oacc[1] = (f32x4){0.f, 0.f, 0.f, 0.f};
    #pragma unroll
    for (int k0 = 0; k0 < 64; k0 += 32) {
      const half8 ap = *(const half8*)&qs[rS + l16][k0 + kg * 8];
      const half8 b0 = *(const half8*)&vt[cS + l16][k0 + kg * 8];
      const half8 b1 = *(const half8*)&vt[cS + 16 + l16][k0 + kg * 8];
      oacc[0] = __builtin_amdgcn_mfma_f32_16x16x32_f16(ap, b0, oacc[0], 0, 0, 0);
      oacc[1] = __builtin_amdgcn_mfma_f32_16x16x32_f16(ap, b1, oacc[1], 0, 0, 0);
    }
    #pragma unroll
    for (int t = 0; t < 2; ++t)
      #pragma unroll
      for (int j = 0; j < 4; ++j)
        ks[rS + kg * 4 + j][cS + t * 16 + l16] = (h16)oacc[t][j];
    __syncthreads();

    #pragma unroll
    for (int k0 = 0; k0 < 64; k0 += 32) {
      half8 ah[4];
      #pragma unroll
      for (int rb = 0; rb < 4; ++rb)
        ah[rb] = *(const half8*)&ks[rb * 16 + l16][k0 + kg * 8];
      #pragma unroll
      for (int cb = 0; cb < 6; ++cb) {
        const int ocol = wv * 96 + cb * 16 + l16;
        const half8 bw = loadw8<WT>(wp + (size_t)ocol * 768 + h * 64 + k0 + kg * 8);
        #pragma unroll
        for (int rb = 0; rb < 4; ++rb)
          acc[rb][cb] = __builtin_amdgcn_mfma_f32_16x16x32_f16(ah[rb], bw, acc[rb][cb], 0, 0, 0);
      }
    }
    __syncthreads();
  }

  float* og = out + (size_t)g * (64 * 768);
  #pragma unroll
  for (int rb = 0; rb < 4; ++rb)
    #pragma unroll
    for (int cb = 0; cb < 6; ++cb) {
      const int col = wv * 96 + cb * 16 + l16;
      #pragma unroll
      for (int j = 0; j < 4; ++j) {
        const int row = rb * 16 + kg * 4 + j;
        og[(size_t)row * 768 + col] = acc[rb][cb][j] + bcol[cb];
      }
    }
}

// ---------------------------------------------------------------- launch
extern "C" void kernel_launch(void* const* d_in, const int* in_sizes, int n_in,
                              void* d_out, int out_size, void* d_ws, size_t ws_size,
                              hipStream_t stream) {
  const float* x     = (const float*)d_in[0];
  const float* wqkv  = (const float*)d_in[1];
  const float* wproj = (const float*)d_in[2];
  const float* bias  = (const float*)d_in[3];
  float* out = (float*)d_out;

  const size_t SZ_WQ = (size_t)2304 * 768 * sizeof(h16);   //   3.54 MB
  const size_t SZ_WP = (size_t)768 * 768 * sizeof(h16);    //   1.18 MB
  const size_t SZ_XH = (size_t)65536 * 768 * sizeof(h16);  // 100.66 MB
  const size_t SZ_O  = (size_t)65536 * 768 * sizeof(h16);  // 100.66 MB

  if (ws_size >= SZ_WQ + SZ_WP + SZ_XH + SZ_O) {
    h16* wq16 = (h16*)d_ws;
    h16* wp16 = (h16*)((char*)d_ws + SZ_WQ);
    h16* xh   = (h16*)((char*)d_ws + SZ_WQ + SZ_WP);
    h16* obuf = (h16*)((char*)d_ws + SZ_WQ + SZ_WP + SZ_XH);

    prep_cvt<<<2048, 256, 0, stream>>>(wqkv, wproj, x, wq16, wp16, xh);
    qkv_attn<<<6144, 512, 0, stream>>>(xh, wq16, obuf);
    gemm_bt64<<<3072, 512, 0, stream>>>(obuf, wp16, bias, out, 6);
  } else if (ws_size >= SZ_WQ + SZ_WP) {
    h16* wq16 = (h16*)d_ws;
    h16* wp16 = (h16*)((char*)d_ws + SZ_WQ);
    prep_w_only<<<512, 256, 0, stream>>>(wqkv, wproj, wq16, wp16);
    fused_fb<h16><<<1024, 512, 0, stream>>>(x, wq16, wp16, bias, out);
  } else {
    fused_fb<float><<<1024, 512, 0, stream>>>(x, wqkv, wproj, bias, out);
  }
}

// Round 13
// 444.511 us; speedup vs baseline: 1.5222x; 1.4453x over previous
//
#include <hip/hip_runtime.h>

// RowAreaAttention split pipeline (round 13 — revert to measured best, round 10):
//  K0 prep_cvt: f32->f16 (w_qkv, w_proj, x)
//  K1 qkv_attn: per (128-row block, head): GEMM {Q|K|V} = xh @ wq_h^T (128x192x768)
//     BK=64 2-phase dbuf, 8 waves (4Mx2N), zero-conflict swizzle; in-WG attention.
//     B staged via global_load_lds (B-direct-from-global failed twice: r11 spill,
//     r12 exposed L2 latency under the per-iteration vmcnt(0) drain).
//  K3 gemm_bt64: out = O @ wp16^T + bias (8-wave BK=64 structure)

#define SCALE 0.125f

typedef _Float16 h16;
typedef h16   half8 __attribute__((ext_vector_type(8)));
typedef float f32x4 __attribute__((ext_vector_type(4)));

typedef const __attribute__((address_space(1))) unsigned int ga_u32;
typedef __attribute__((address_space(3))) unsigned int ls_u32;

// swizzled h16 index into a [R][64] tile: 16B chunk (c>>3) XOR'd with (r&7)
#define SWZ(r, c) (((r) << 6) + ((((c) >> 3) ^ ((r) & 7)) << 3) + ((c) & 7))

// ---------------------------------------------------------------- K0: prep
__device__ __forceinline__ void cvt8(const float* __restrict__ s,
                                     h16* __restrict__ d, int i) {
  const float4 a = ((const float4*)s)[2 * i];
  const float4 b = ((const float4*)s)[2 * i + 1];
  half8 r;
  r[0] = (h16)a.x; r[1] = (h16)a.y; r[2] = (h16)a.z; r[3] = (h16)a.w;
  r[4] = (h16)b.x; r[5] = (h16)b.y; r[6] = (h16)b.z; r[7] = (h16)b.w;
  ((half8*)d)[i] = r;
}

__global__ void prep_cvt(const float* __restrict__ wq, const float* __restrict__ wp,
                         const float* __restrict__ x,
                         h16* __restrict__ wq16, h16* __restrict__ wp16,
                         h16* __restrict__ xh) {
  const int stride = gridDim.x * blockDim.x;
  const int t0 = blockIdx.x * blockDim.x + threadIdx.x;
  for (int i = t0; i < 221184; i += stride) cvt8(wq, wq16, i);   // 2304*768
  for (int i = t0; i < 73728;  i += stride) cvt8(wp, wp16, i);   // 768*768
  for (int i = t0; i < 6291456; i += stride) cvt8(x, xh, i);     // 65536*768
}

__global__ void prep_w_only(const float* __restrict__ wq, const float* __restrict__ wp,
                            h16* __restrict__ wq16, h16* __restrict__ wp16) {
  const int stride = gridDim.x * blockDim.x;
  const int t0 = blockIdx.x * blockDim.x + threadIdx.x;
  for (int i = t0; i < 221184; i += stride) cvt8(wq, wq16, i);
  for (int i = t0; i < 73728;  i += stride) cvt8(wp, wp16, i);
}

// -------------------------------------- K1: fused QKV-GEMM + attention per head
// Grid: 512 row-tiles x 12 heads, WG = 512 thr (8 waves, 4M x 2N).
// GEMM: C(128x192) = A(128x768) @ B(192x768)^T, BK=64, 12 outer steps, 2-phase
//   dbuf, ONE vmcnt(0)+barrier per tile. Swizzle proven zero-conflict.
// Attn overlay (first 48 KB, XOR-swizzled [.][64] tiles, no padding):
//   sQ[128][64] (Q->P), sK[128][64] (K->O), sV[2][64][64] (V^T per group).
// Measured (round 9/10): 275 us, MfmaUtil 43%, VGPR 60, occupancy 44%.
__global__ __launch_bounds__(512, 4)
void qkv_attn(const h16* __restrict__ A,      // xh (65536 x 768)
              const h16* __restrict__ B,      // wq16 (2304 x 768)
              h16* __restrict__ O) {          // obuf (65536 x 768)
  __shared__ h16 smem[40960];                 // 80 KB union
  h16* As0 = smem;                            // GEMM: [2][8192]  ([128][64] x2)
  h16* Bs0 = smem + 16384;                    // GEMM: [2][12288] ([192][64] x2)
  h16* sQ  = smem;                            // attn: [128][64] swizzled
  h16* sK  = smem + 8192;                     // attn: [128][64] swizzled
  h16* sV  = smem + 16384;                    // attn: [2][64][64] swizzled (V^T)

  const int nwg = gridDim.x;                  // 6144
  const int bid = blockIdx.x;
  const int wg  = (bid & 7) * (nwg >> 3) + (bid >> 3);   // XCD-chunked swizzle
  const int mt = wg / 12, h = wg - mt * 12;
  const int m0 = mt * 128;

  const int tid  = threadIdx.x;
  const int lane = tid & 63;
  const int wv   = tid >> 6;       // 0..7
  const int l16  = lane & 15;
  const int kg   = lane >> 4;
  const int wr   = wv & 3;         // M quarter (rows wr*32, 2 frags)
  const int wc   = wv >> 2;        // N half   (cols wc*96, 6 frags)

  // ---- staging: thread covers chunk (row = i*64 + tid>>3, slot = tid&7)
  const int srow = tid >> 3;                  // 0..63
  const int slot = tid & 7;
  const int cg   = slot ^ (srow & 7);         // pre-swizzled src col-group
  const h16* pA[2];
  const h16* pB[3];
  int loA[2], loB[3];
  #pragma unroll
  for (int i = 0; i < 2; ++i) {
    const int r = i * 64 + srow;                         // 0..127
    pA[i]  = A + (size_t)(m0 + r) * 768 + cg * 8;
    loA[i] = r * 64 + slot * 8;
  }
  #pragma unroll
  for (int i = 0; i < 3; ++i) {
    const int r  = i * 64 + srow;                        // 0..191
    const int gr = (r >> 6) * 768 + h * 64 + (r & 63);   // global wq row
    pB[i]  = B + (size_t)gr * 768 + cg * 8;
    loB[i] = r * 64 + slot * 8;
  }

#define GLDS(srcp, ldsp)                                                       \
  __builtin_amdgcn_global_load_lds((ga_u32*)(const void*)(srcp),               \
                                   (ls_u32*)(void*)(ldsp), 16, 0, 0)
#define STAGE(bf, kt)                                                          \
  do {                                                                         \
    GLDS(pA[0] + (kt) * 64, &As0[(bf) * 8192 + loA[0]]);                       \
    GLDS(pA[1] + (kt) * 64, &As0[(bf) * 8192 + loA[1]]);                       \
    GLDS(pB[0] + (kt) * 64, &Bs0[(bf) * 12288 + loB[0]]);                      \
    GLDS(pB[1] + (kt) * 64, &Bs0[(bf) * 12288 + loB[1]]);                      \
    GLDS(pB[2] + (kt) * 64, &Bs0[(bf) * 12288 + loB[2]]);                      \
  } while (0)

  // ---- fragment read offsets (h16 units, swizzled; frag row&7 == l16&7)
  const int aBase = (wr * 32 + l16) * 64;     // + mi*1024 + axor[ks]
  const int bBase = (wc * 96 + l16) * 64;     // + ni*1024 + axor[ks]
  int axor[2];
  #pragma unroll
  for (int ks = 0; ks < 2; ++ks)
    axor[ks] = ((ks * 4 + kg) ^ (l16 & 7)) * 8;

  f32x4 acc[2][6];
  #pragma unroll
  for (int mi = 0; mi < 2; ++mi)
    #pragma unroll
    for (int ni = 0; ni < 6; ++ni)
      acc[mi][ni] = (f32x4){0.f, 0.f, 0.f, 0.f};

  STAGE(0, 0);
  asm volatile("s_waitcnt vmcnt(0)" ::: "memory");
  __syncthreads();

  int cur = 0;
  for (int t = 0; t < 12; ++t) {
    if (t < 11) STAGE(cur ^ 1, t + 1);
    const h16* Ac = As0 + cur * 8192;
    const h16* Bc = Bs0 + cur * 12288;
    #pragma unroll
    for (int ks = 0; ks < 2; ++ks) {
      half8 af[2], bf8[6];
      #pragma unroll
      for (int mi = 0; mi < 2; ++mi)
        af[mi] = *(const half8*)&Ac[aBase + mi * 1024 + axor[ks]];
      #pragma unroll
      for (int ni = 0; ni < 6; ++ni)
        bf8[ni] = *(const half8*)&Bc[bBase + ni * 1024 + axor[ks]];
      #pragma unroll
      for (int mi = 0; mi < 2; ++mi)
        #pragma unroll
        for (int ni = 0; ni < 6; ++ni)
          acc[mi][ni] = __builtin_amdgcn_mfma_f32_16x16x32_f16(af[mi], bf8[ni], acc[mi][ni], 0, 0, 0);
    }
    asm volatile("s_waitcnt vmcnt(0)" ::: "memory");
    __syncthreads();
    cur ^= 1;
  }
#undef STAGE
#undef GLDS

  // ---- scatter acc -> sQ / sK / sV (swizzled; all waves past final LDS reads)
  #pragma unroll
  for (int mi = 0; mi < 2; ++mi) {
    const int rowb = wr * 32 + mi * 16 + kg * 4;     // token row in 128
    const int r6   = rowb & 63;                      // token within group
    const int g2s  = rowb >> 6;                      // group of this row
    #pragma unroll
    for (int ni = 0; ni < 6; ++ni) {
      const int cbase = wc * 96 + ni * 16;           // wave-uniform, 0..176
      const int sel = cbase >> 6;
      const int d   = (cbase & 63) + l16;
      if (sel == 0) {
        #pragma unroll
        for (int j = 0; j < 4; ++j) sQ[SWZ(rowb + j, d)] = (h16)acc[mi][ni][j];
      } else if (sel == 1) {
        #pragma unroll
        for (int j = 0; j < 4; ++j) sK[SWZ(rowb + j, d)] = (h16)acc[mi][ni][j];
      } else {
        #pragma unroll
        for (int j = 0; j < 4; ++j) sV[g2s * 4096 + SWZ(d, r6 + j)] = (h16)acc[mi][ni][j];
      }
    }
  }
  __syncthreads();

  // ---- attention: wave handles 16 q-rows [wv*16, wv*16+16), group wv>>2
  const int qr0 = wv * 16;
  const int g2  = wv >> 2;
  const h16* sKg = sK + g2 * 4096;
  const h16* sVg = sV + g2 * 4096;

  f32x4 sacc[4];
  #pragma unroll
  for (int cb = 0; cb < 4; ++cb) sacc[cb] = (f32x4){0.f, 0.f, 0.f, 0.f};
  #pragma unroll
  for (int ks = 0; ks < 2; ++ks) {
    const half8 aq = *(const half8*)&sQ[(qr0 + l16) * 64 + axor[ks]];
    #pragma unroll
    for (int cb = 0; cb < 4; ++cb) {
      const half8 kf = *(const half8*)&sKg[(cb * 16 + l16) * 64 + axor[ks]];
      sacc[cb] = __builtin_amdgcn_mfma_f32_16x16x32_f16(aq, kf, sacc[cb], 0, 0, 0);
    }
  }

  // max-free softmax (|S*scale| << 88): rows qr0 + kg*4 + j
  float e[4][4], rs[4];
  #pragma unroll
  for (int j = 0; j < 4; ++j) {
    float t = 0.f;
    #pragma unroll
    for (int cb = 0; cb < 4; ++cb) { e[cb][j] = __expf(sacc[cb][j] * SCALE); t += e[cb][j]; }
    rs[j] = t;
  }
  #pragma unroll
  for (int m = 1; m < 16; m <<= 1)
    #pragma unroll
    for (int j = 0; j < 4; ++j) rs[j] += __shfl_xor(rs[j], m);
  #pragma unroll
  for (int j = 0; j < 4; ++j) rs[j] = __fdividef(1.0f, rs[j]);

  // P -> sQ (own rows only; no cross-wave readers of these rows)
  #pragma unroll
  for (int cb = 0; cb < 4; ++cb)
    #pragma unroll
    for (int j = 0; j < 4; ++j)
      sQ[SWZ(qr0 + kg * 4 + j, cb * 16 + l16)] = (h16)(e[cb][j] * rs[j]);
  __syncthreads();   // all K-reads done before O overwrites sK

  // ---- O = P V
  f32x4 oacc[4];
  #pragma unroll
  for (int cb = 0; cb < 4; ++cb) oacc[cb] = (f32x4){0.f, 0.f, 0.f, 0.f};
  #pragma unroll
  for (int ks = 0; ks < 2; ++ks) {
    const half8 ap = *(const half8*)&sQ[(qr0 + l16) * 64 + axor[ks]];
    #pragma unroll
    for (int cb = 0; cb < 4; ++cb) {
      const half8 vf = *(const half8*)&sVg[(cb * 16 + l16) * 64 + axor[ks]];
      oacc[cb] = __builtin_amdgcn_mfma_f32_16x16x32_f16(ap, vf, oacc[cb], 0, 0, 0);
    }
  }

  // O -> sK (dead), then chunk-permuted vectorized store (coalesced per segment)
  #pragma unroll
  for (int cb = 0; cb < 4; ++cb)
    #pragma unroll
    for (int j = 0; j < 4; ++j)
      sK[SWZ(qr0 + kg * 4 + j, cb * 16 + l16)] = (h16)oacc[cb][j];
  __syncthreads();
  #pragma unroll
  for (int c = tid; c < 1024; c += 512) {
    const int row = c >> 3, sl = c & 7;
    const int gch = sl ^ (row & 7);            // un-swizzle via permuted dst chunk
    *(half8*)(O + (size_t)(m0 + row) * 768 + h * 64 + gch * 8) =
        *(const half8*)&sK[row * 64 + sl * 8];
  }
}

// --------------------------- K3: gemm_bt64 (8-wave BK=64 structure)
__global__ __launch_bounds__(512, 4)
void gemm_bt64(const h16* __restrict__ A,
               const h16* __restrict__ B,
               const float* __restrict__ bias,
               float* __restrict__ C,
               int ntiles) {
  __shared__ h16 As0[2][8192];   // [128][64] swizzled x2
  __shared__ h16 Bs0[2][8192];

  const int nwg = gridDim.x;
  const int bid = blockIdx.x;
  const int wg  = (bid & 7) * (nwg >> 3) + (bid >> 3);
  const int mt = wg / ntiles, nt = wg - mt * ntiles;
  const int m0 = mt * 128, n0 = nt * 128;

  const int tid  = threadIdx.x;
  const int lane = tid & 63;
  const int wv   = tid >> 6;       // 0..7
  const int l16  = lane & 15;
  const int kg   = lane >> 4;
  const int wr   = wv & 3;         // M quarter (rows wr*32, 2 frags)
  const int wc   = wv >> 2;        // N half   (cols wc*64, 4 frags)

  const int srow = tid >> 3;
  const int slot = tid & 7;
  const int cg   = slot ^ (srow & 7);
  const h16* pA[2];
  const h16* pB[2];
  int lo[2];
  #pragma unroll
  for (int i = 0; i < 2; ++i) {
    const int r = i * 64 + srow;                 // 0..127
    pA[i] = A + (size_t)(m0 + r) * 768 + cg * 8;
    pB[i] = B + (size_t)(n0 + r) * 768 + cg * 8;
    lo[i] = r * 64 + slot * 8;
  }

#define GLDS(srcp, ldsp)                                                       \
  __builtin_amdgcn_global_load_lds((ga_u32*)(const void*)(srcp),               \
                                   (ls_u32*)(void*)(ldsp), 16, 0, 0)
#define STAGE(bf, kt)                                                          \
  do {                                                                         \
    GLDS(pA[0] + (kt) * 64, &As0[bf][lo[0]]);                                  \
    GLDS(pA[1] + (kt) * 64, &As0[bf][lo[1]]);                                  \
    GLDS(pB[0] + (kt) * 64, &Bs0[bf][lo[0]]);                                  \
    GLDS(pB[1] + (kt) * 64, &Bs0[bf][lo[1]]);                                  \
  } while (0)

  const int aBase = (wr * 32 + l16) * 64;
  const int bBase = (wc * 64 + l16) * 64;
  int axor[2];
  #pragma unroll
  for (int ks = 0; ks < 2; ++ks)
    axor[ks] = ((ks * 4 + kg) ^ (l16 & 7)) * 8;

  f32x4 acc[2][4];
  #pragma unroll
  for (int mi = 0; mi < 2; ++mi)
    #pragma unroll
    for (int ni = 0; ni < 4; ++ni)
      acc[mi][ni] = (f32x4){0.f, 0.f, 0.f, 0.f};

  STAGE(0, 0);
  asm volatile("s_waitcnt vmcnt(0)" ::: "memory");
  __syncthreads();

  int cur = 0;
  for (int t = 0; t < 12; ++t) {
    if (t < 11) STAGE(cur ^ 1, t + 1);
    #pragma unroll
    for (int ks = 0; ks < 2; ++ks) {
      half8 af[2], bf8[4];
      #pragma unroll
      for (int mi = 0; mi < 2; ++mi)
        af[mi] = *(const half8*)&As0[cur][aBase + mi * 1024 + axor[ks]];
      #pragma unroll
      for (int ni = 0; ni < 4; ++ni)
        bf8[ni] = *(const half8*)&Bs0[cur][bBase + ni * 1024 + axor[ks]];
      #pragma unroll
      for (int mi = 0; mi < 2; ++mi)
        #pragma unroll
        for (int ni = 0; ni < 4; ++ni)
          acc[mi][ni] = __builtin_amdgcn_mfma_f32_16x16x32_f16(af[mi], bf8[ni], acc[mi][ni], 0, 0, 0);
    }
    asm volatile("s_waitcnt vmcnt(0)" ::: "memory");
    __syncthreads();
    cur ^= 1;
  }
#undef STAGE
#undef GLDS

  float bv[4];
  #pragma unroll
  for (int ni = 0; ni < 4; ++ni) bv[ni] = bias[n0 + wc * 64 + ni * 16 + l16];
  #pragma unroll
  for (int mi = 0; mi < 2; ++mi) {
    #pragma unroll
    for (int ni = 0; ni < 4; ++ni) {
      const int col = n0 + wc * 64 + ni * 16 + l16;
      #pragma unroll
      for (int j = 0; j < 4; ++j) {
        const int row = m0 + wr * 32 + mi * 16 + kg * 4 + j;
        C[(size_t)row * 768 + col] = acc[mi][ni][j] + bv[ni];
      }
    }
  }
}

// ------------------------------------------- fallback: fused kernel (small ws)
template <typename WT>
__device__ __forceinline__ half8 loadw8(const WT* p);
template <>
__device__ __forceinline__ half8 loadw8<h16>(const h16* p) { return *(const half8*)p; }
template <>
__device__ __forceinline__ half8 loadw8<float>(const float* p) {
  const float4 a = *(const float4*)p;
  const float4 b = *(const float4*)(p + 4);
  half8 r;
  r[0] = (h16)a.x; r[1] = (h16)a.y; r[2] = (h16)a.z; r[3] = (h16)a.w;
  r[4] = (h16)b.x; r[5] = (h16)b.y; r[6] = (h16)b.z; r[7] = (h16)b.w;
  return r;
}

template <typename WT>
__launch_bounds__(512, 2)
__global__ void fused_fb(const float* __restrict__ x,
                         const WT* __restrict__ wq,
                         const WT* __restrict__ wp,
                         const float* __restrict__ bias,
                         float* __restrict__ out) {
  __shared__ h16   xs[64][776];
  __shared__ h16   qs[64][72];
  __shared__ h16   ks[64][72];
  __shared__ h16   vt[64][72];
  __shared__ float sS[64][68];

  const int g = blockIdx.x, tid = threadIdx.x;
  const int wv = tid >> 6, lane = tid & 63, l16 = lane & 15, kg = lane >> 4;

  const float* xg = x + (size_t)g * (64 * 768);
  #pragma unroll
  for (int i = 0; i < 24; ++i) {
    const int idx = tid + i * 512;
    const int row = idx / 192;
    const int c4  = (idx - row * 192) * 4;
    const float4 v = ((const float4*)xg)[idx];
    h16* p = &xs[row][c4];
    p[0] = (h16)v.x; p[1] = (h16)v.y; p[2] = (h16)v.z; p[3] = (h16)v.w;
  }

  f32x4 acc[4][6];
  #pragma unroll
  for (int a = 0; a < 4; ++a)
    #pragma unroll
    for (int b = 0; b < 6; ++b) acc[a][b] = (f32x4){0.f, 0.f, 0.f, 0.f};

  float bcol[6];
  #pragma unroll
  for (int cb = 0; cb < 6; ++cb) bcol[cb] = bias[wv * 96 + cb * 16 + l16];

  const int r0 = (wv & 1) * 32, c0 = (wv >> 1) * 48;
  const int rS = (wv >> 1) * 16, cS = (wv & 1) * 32;
  __syncthreads();

  for (int h = 0; h < 12; ++h) {
    f32x4 facc[2][3];
    #pragma unroll
    for (int a = 0; a < 2; ++a)
      #pragma unroll
      for (int b = 0; b < 3; ++b) facc[a][b] = (f32x4){0.f, 0.f, 0.f, 0.f};
    int wrow[3];
    #pragma unroll
    for (int cb = 0; cb < 3; ++cb) {
      const int n = c0 + cb * 16;
      wrow[cb] = (n >> 6) * 768 + h * 64 + (n & 63) + l16;
    }
    for (int k0 = 0; k0 < 768; k0 += 32) {
      const half8 a0 = *(const half8*)&xs[r0 + l16][k0 + kg * 8];
      const half8 a1 = *(const half8*)&xs[r0 + 16 + l16][k0 + kg * 8];
      #pragma unroll
      for (int cb = 0; cb < 3; ++cb) {
        const half8 b = loadw8<WT>(wq + (size_t)wrow[cb] * 768 + k0 + kg * 8);
        facc[0][cb] = __builtin_amdgcn_mfma_f32_16x16x32_f16(a0, b, facc[0][cb], 0, 0, 0);
        facc[1][cb] = __builtin_amdgcn_mfma_f32_16x16x32_f16(a1, b, facc[1][cb], 0, 0, 0);
      }
    }
    #pragma unroll
    for (int rb = 0; rb < 2; ++rb)
      #pragma unroll
      for (int cb = 0; cb < 3; ++cb) {
        const int col = c0 + cb * 16 + l16;
        const int rowb = r0 + rb * 16 + kg * 4;
        if (col < 64) {
          #pragma unroll
          for (int j = 0; j < 4; ++j) qs[rowb + j][col] = (h16)facc[rb][cb][j];
        } else if (col < 128) {
          #pragma unroll
          for (int j = 0; j < 4; ++j) ks[rowb + j][col - 64] = (h16)facc[rb][cb][j];
        } else {
          #pragma unroll
          for (int j = 0; j < 4; ++j) vt[col - 128][rowb + j] = (h16)facc[rb][cb][j];
        }
      }
    __syncthreads();

    f32x4 sacc[2];
    sacc[0] = (f32x4){0.f, 0.f, 0.f, 0.f};
    sacc[1] = (f32x4){0.f, 0.f, 0.f, 0.f};
    #pragma unroll
    for (int k0 = 0; k0 < 64; k0 += 32) {
      const half8 aq = *(const half8*)&qs[rS + l16][k0 + kg * 8];
      const half8 b0 = *(const half8*)&ks[cS + l16][k0 + kg * 8];
      const half8 b1 = *(const half8*)&ks[cS + 16 + l16][k0 + kg * 8];
      sacc[0] = __builtin_amdgcn_mfma_f32_16x16x32_f16(aq, b0, sacc[0], 0, 0, 0);
      sacc[1] = __builtin_amdgcn_mfma_f32_16x16x32_f16(aq, b1, sacc[1], 0, 0, 0);
    }
    #pragma unroll
    for (int t = 0; t < 2; ++t)
      #pragma unroll
      for (int j = 0; j < 4; ++j)
        sS[rS + kg * 4 + j][cS + t * 16 + l16] = sacc[t][j] * SCALE;
    __syncthreads();

    {
      const int row = tid >> 3, j0 = (tid & 7) * 8;
      float v0[8];
      #pragma unroll
      for (int i = 0; i < 8; ++i) v0[i] = sS[row][j0 + i];
      float m = v0[0];
      #pragma unroll
      for (int i = 1; i < 8; ++i) m = fmaxf(m, v0[i]);
      m = fmaxf(m, __shfl_xor(m, 1));
      m = fmaxf(m, __shfl_xor(m, 2));
      m = fmaxf(m, __shfl_xor(m, 4));
      float e[8], ssum = 0.f;
      #pragma unroll
      for (int i = 0; i < 8; ++i) { e[i] = __expf(v0[i] - m); ssum += e[i]; }
      ssum += __shfl_xor(ssum, 1);
      ssum += __shfl_xor(ssum, 2);
      ssum += __shfl_xor(ssum, 4);
      const float inv = 1.0f / ssum;
      #pragma unroll
      for (int i = 0; i < 8; ++i) qs[row][j0 + i] = (h16)(e[i] * inv);
    }
    __syncthreads();

    f32x4 oacc[2];
    oacc[0] = (f32x4){0.f, 0.f, 0.f, 0.f};
    oacc[1] = (f32x4){0.f, 0.f, 0.f, 0.f};
    #pragma unroll
    for (int k0 = 0; k0 < 64; k0 += 32) {
      const half8 ap = *(const half8*)&qs[rS + l16][k0 + kg * 8];
      const half8 b0 = *(const half8*)&vt[cS + l16][k0 + kg * 8];
      const half8 b1 = *(const half8*)&vt[cS + 16 + l16][k0 + kg * 8];
      oacc[0] = __builtin_amdgcn_mfma_f32_16x16x32_f16(ap, b0, oacc[0], 0, 0, 0);
      oacc[1] = __builtin_amdgcn_mfma_f32_16x16x32_f16(ap, b1, oacc[1], 0, 0, 0);
    }
    #pragma unroll
    for (int t = 0; t < 2; ++t)
      #pragma unroll
      for (int j = 0; j < 4; ++j)
        ks[rS + kg * 4 + j][cS + t * 16 + l16] = (h16)oacc[t][j];
    __syncthreads();

    #pragma unroll
    for (int k0 = 0; k0 < 64; k0 += 32) {
      half8 ah[4];
      #pragma unroll
      for (int rb = 0; rb < 4; ++rb)
        ah[rb] = *(const half8*)&ks[rb * 16 + l16][k0 + kg * 8];
      #pragma unroll
      for (int cb = 0; cb < 6; ++cb) {
        const int ocol = wv * 96 + cb * 16 + l16;
        const half8 bw = loadw8<WT>(wp + (size_t)ocol * 768 + h * 64 + k0 + kg * 8);
        #pragma unroll
        for (int rb = 0; rb < 4; ++rb)
          acc[rb][cb] = __builtin_amdgcn_mfma_f32_16x16x32_f16(ah[rb], bw, acc[rb][cb], 0, 0, 0);
      }
    }
    __syncthreads();
  }

  float* og = out + (size_t)g * (64 * 768);
  #pragma unroll
  for (int rb = 0; rb < 4; ++rb)
    #pragma unroll
    for (int cb = 0; cb < 6; ++cb) {
      const int col = wv * 96 + cb * 16 + l16;
      #pragma unroll
      for (int j = 0; j < 4; ++j) {
        const int row = rb * 16 + kg * 4 + j;
        og[(size_t)row * 768 + col] = acc[rb][cb][j] + bcol[cb];
      }
    }
}

// ---------------------------------------------------------------- launch
extern "C" void kernel_launch(void* const* d_in, const int* in_sizes, int n_in,
                              void* d_out, int out_size, void* d_ws, size_t ws_size,
                              hipStream_t stream) {
  const float* x     = (const float*)d_in[0];
  const float* wqkv  = (const float*)d_in[1];
  const float* wproj = (const float*)d_in[2];
  const float* bias  = (const float*)d_in[3];
  float* out = (float*)d_out;

  const size_t SZ_WQ = (size_t)2304 * 768 * sizeof(h16);   //   3.54 MB
  const size_t SZ_WP = (size_t)768 * 768 * sizeof(h16);    //   1.18 MB
  const size_t SZ_XH = (size_t)65536 * 768 * sizeof(h16);  // 100.66 MB
  const size_t SZ_O  = (size_t)65536 * 768 * sizeof(h16);  // 100.66 MB

  if (ws_size >= SZ_WQ + SZ_WP + SZ_XH + SZ_O) {
    h16* wq16 = (h16*)d_ws;
    h16* wp16 = (h16*)((char*)d_ws + SZ_WQ);
    h16* xh   = (h16*)((char*)d_ws + SZ_WQ + SZ_WP);
    h16* obuf = (h16*)((char*)d_ws + SZ_WQ + SZ_WP + SZ_XH);

    prep_cvt<<<2048, 256, 0, stream>>>(wqkv, wproj, x, wq16, wp16, xh);
    qkv_attn<<<6144, 512, 0, stream>>>(xh, wq16, obuf);
    gemm_bt64<<<3072, 512, 0, stream>>>(obuf, wp16, bias, out, 6);
  } else if (ws_size >= SZ_WQ + SZ_WP) {
    h16* wq16 = (h16*)d_ws;
    h16* wp16 = (h16*)((char*)d_ws + SZ_WQ);
    prep_w_only<<<512, 256, 0, stream>>>(wqkv, wproj, wq16, wp16);
    fused_fb<h16><<<1024, 512, 0, stream>>>(x, wq16, wp16, bias, out);
  } else {
    fused_fb<float><<<1024, 512, 0, stream>>>(x, wqkv, wproj, bias, out);
  }
}